// Round 5
// baseline (179.143 us; speedup 1.0000x reference)
//
#include <hip/hip_runtime.h>
#include <hip/hip_bf16.h>
#include <math.h>

#define M_  4
#define B_  2048
#define K_  32
#define D_  256
#define DZ_ 128
#define PAD 68

// ---------------------------------------------------------------------------
// K0: Wqk[m][z][d] = sum_e W_Q[z][e] * W_K[m][d][e]   (fold W_Q into W_K)
// ---------------------------------------------------------------------------
__global__ void __launch_bounds__(256) k0_wqk(const float* __restrict__ W_Q,
                                              const float* __restrict__ W_K,
                                              float* __restrict__ Wqk) {
    int mz = blockIdx.x;
    int m = mz >> 7, z = mz & 127;
    int d = threadIdx.x;
    __shared__ float wq[D_];
    wq[d] = W_Q[z * D_ + d];
    __syncthreads();
    const float* wk = W_K + (m * D_ + d) * D_;
    float acc = 0.f;
#pragma unroll 8
    for (int e = 0; e < D_; ++e) acc = fmaf(wq[e], wk[e], acc);
    Wqk[(m * DZ_ + z) * D_ + d] = acc;
}

// ---------------------------------------------------------------------------
// K1: Qk[m][b][d] = sum_z z_anc[b][z] * Wqk[m][z][d]
// ---------------------------------------------------------------------------
__global__ void __launch_bounds__(256) k1_qk(const float* __restrict__ z_anc,
                                             const float* __restrict__ Wqk,
                                             float* __restrict__ Qk) {
    int m = blockIdx.z;
    int b0 = blockIdx.x * 64, d0 = blockIdx.y * 64;
    int t = threadIdx.x, tx = t & 15, ty = t >> 4;
    __shared__ float As[64 * PAD];
    __shared__ float Bs[64 * PAD];
    float c[4][4] = {};
    for (int kc = 0; kc < DZ_; kc += 64) {
#pragma unroll
        for (int it = 0; it < 4; ++it) {
            int s = it * 256 + t, bi = s >> 4, k4 = (s & 15) * 4;
            *(float4*)&As[bi * PAD + k4] =
                *(const float4*)&z_anc[(b0 + bi) * DZ_ + kc + k4];
        }
#pragma unroll
        for (int it = 0; it < 4; ++it) {
            int s = it * 256 + t, kk = s >> 4, d4 = (s & 15) * 4;
            *(float4*)&Bs[kk * PAD + d4] =
                *(const float4*)&Wqk[(m * DZ_ + kc + kk) * D_ + d0 + d4];
        }
        __syncthreads();
#pragma unroll 4
        for (int kk = 0; kk < 64; ++kk) {
            float a[4];
#pragma unroll
            for (int i = 0; i < 4; ++i) a[i] = As[(ty * 4 + i) * PAD + kk];
            float4 b4 = *(const float4*)&Bs[kk * PAD + tx * 4];
#pragma unroll
            for (int i = 0; i < 4; ++i) {
                c[i][0] = fmaf(a[i], b4.x, c[i][0]);
                c[i][1] = fmaf(a[i], b4.y, c[i][1]);
                c[i][2] = fmaf(a[i], b4.z, c[i][2]);
                c[i][3] = fmaf(a[i], b4.w, c[i][3]);
            }
        }
        __syncthreads();
    }
#pragma unroll
    for (int i = 0; i < 4; ++i) {
        float4 v = make_float4(c[i][0], c[i][1], c[i][2], c[i][3]);
        *(float4*)&Qk[(m * B_ + b0 + ty * 4 + i) * D_ + d0 + tx * 4] = v;
    }
}

// ---------------------------------------------------------------------------
// Direct global->LDS copy, 16B per lane, zero VGPR cost, fire-and-forget.
// LDS dest is wave-uniform base + lane*16 (m104 semantics); global src is
// per-lane. Linear LDS layout matches lane order by construction.
// ---------------------------------------------------------------------------
__device__ __forceinline__ void gl_lds16(const float* g, float* lds) {
    __builtin_amdgcn_global_load_lds(
        (const __attribute__((address_space(1))) void*)g,
        (__attribute__((address_space(3))) void*)lds, 16, 0, 0);
}

// ---------------------------------------------------------------------------
// K2: one block per (b,m), m fastest. h tile (32KB) + lbl tile (32KB) staged
// via global_load_lds (R3/R4 evidence: register-path loads get sunk by the
// allocator -> serial latency chains; direct-to-LDS can't be sunk, all 16
// issues/thread outstanding at once). One vmcnt(0) drain at the barrier.
// ---------------------------------------------------------------------------
__global__ void __launch_bounds__(256) k2_main(
    const float* __restrict__ h_nei, const float* __restrict__ ew_anc,
    const float* __restrict__ vmask, const float* __restrict__ lbl_delta,
    const float* __restrict__ lbl_w, const float* __restrict__ Qk,
    const float* __restrict__ log_vw,
    float* __restrict__ hbar, float* __restrict__ lblp)
{
    int bm = blockIdx.x;
    int b = bm >> 2, m = bm & 3;
    int t = threadIdx.x, w = t >> 6, l = t & 63;
    __shared__ float hs[K_ * D_];     // 32 KB: h[k][d]
    __shared__ float ls[K_ * D_];     // 32 KB: lbl[k][d] (for this m)
    __shared__ float sc[K_], at[K_];

    // --- stage both tiles: wave w issues rows k = w*8+j (uniform base) ---
    const float* hb  = h_nei + ((size_t)(m * B_ + b)) * (K_ * D_);
    const float* ldb = lbl_delta + (size_t)b * (K_ * M_ * D_) + m * D_;
#pragma unroll
    for (int j = 0; j < 8; ++j) {
        int k = w * 8 + j;
        gl_lds16(hb + k * D_ + 4 * l, hs + k * D_);
        gl_lds16(ldb + (size_t)k * (M_ * D_) + 4 * l, ls + k * D_);
    }

    // --- overlap: register loads + uniform vw while tiles are in flight ---
    float4 q4 = *(const float4*)&Qk[(m * B_ + b) * D_ + 4 * l];
    float ew_v = 0.f, lw_v = 0.f, vm_v = 1.f;
    if (t < K_) {
        int idx = (b * K_ + t) * M_ + m;
        ew_v = ew_anc[idx];
        lw_v = lbl_w[idx];
        vm_v = vmask[idx];
    }
    float lv0 = log_vw[0], lv1 = log_vw[1], lv2 = log_vw[2], lv3 = log_vw[3];
    float mv = fmaxf(fmaxf(lv0, lv1), fmaxf(lv2, lv3));
    float e0 = expf(lv0 - mv), e1 = expf(lv1 - mv),
          e2 = expf(lv2 - mv), e3 = expf(lv3 - mv);
    float vw_m = ((m == 0) ? e0 : (m == 1) ? e1 : (m == 2) ? e2 : e3)
                 / (e0 + e1 + e2 + e3);

    __syncthreads();   // drains vmcnt(0): all load_lds landed, all waves

    // --- scores: wave w owns rows k=w*8+j; b128 row reads (conflict-free) ---
#pragma unroll
    for (int j = 0; j < 8; ++j) {
        int k = w * 8 + j;
        float4 h4 = *(const float4*)&hs[k * D_ + 4 * l];
        float v = h4.x * q4.x + h4.y * q4.y + h4.z * q4.z + h4.w * q4.w;
        v += __shfl_xor(v, 32); v += __shfl_xor(v, 16); v += __shfl_xor(v, 8);
        v += __shfl_xor(v, 4);  v += __shfl_xor(v, 2);  v += __shfl_xor(v, 1);
        if (l == 0) sc[k] = v;
    }
    __syncthreads();

    // --- softmax over K=32 in lanes 0..31 of wave 0 ---
    if (t < K_) {
        float s = (vm_v == 0.f) ? -1e9f
                                : sc[t] * 0.0625f + logf(ew_v + 1e-6f) + lw_v;
        float mx = s;
        mx = fmaxf(mx, __shfl_xor(mx, 16)); mx = fmaxf(mx, __shfl_xor(mx, 8));
        mx = fmaxf(mx, __shfl_xor(mx, 4));  mx = fmaxf(mx, __shfl_xor(mx, 2));
        mx = fmaxf(mx, __shfl_xor(mx, 1));
        float ee = expf(s - mx);
        float ds = ee;
        ds += __shfl_xor(ds, 16); ds += __shfl_xor(ds, 8); ds += __shfl_xor(ds, 4);
        ds += __shfl_xor(ds, 2);  ds += __shfl_xor(ds, 1);
        at[t] = (ee / ds) * vw_m;       // fold vw[m]
    }
    __syncthreads();

    // --- weighted sums: thread t owns column d=t (2-way bank alias = free) ---
    float ah = 0.f, al = 0.f;
#pragma unroll 8
    for (int k = 0; k < K_; ++k) {
        float a = at[k];                // broadcast read
        ah = fmaf(a, hs[k * D_ + t], ah);
        al = fmaf(a, ls[k * D_ + t], al);
    }
    hbar[(size_t)b * (M_ * D_) + m * D_ + t] = ah;
    lblp[((size_t)m * B_ + b) * D_ + t] = al;
}

// ---------------------------------------------------------------------------
// K3: out[b][e] = sum_kk hbar[b][kk]*W_Vflat[kk][e] + sum_m lblp[m][b][e]
// 16x64 tiles, grid (128,4)=512 blocks (2/CU) for latency hiding.
// ---------------------------------------------------------------------------
__global__ void __launch_bounds__(256) k3_gemm(const float* __restrict__ hbar,
                                               const float* __restrict__ W_V,
                                               const float* __restrict__ lblp,
                                               float* __restrict__ out) {
    int b0 = blockIdx.x * 16, e0 = blockIdx.y * 64;
    int t = threadIdx.x, tx = t & 15, ty = t >> 4;
    __shared__ float As[16 * PAD];
    __shared__ float Bs[64 * PAD];
    float c0 = 0.f, c1 = 0.f, c2 = 0.f, c3 = 0.f;
    for (int kc = 0; kc < M_ * D_; kc += 64) {
        {
            int bi = t >> 4, k4 = (t & 15) * 4;
            *(float4*)&As[bi * PAD + k4] =
                *(const float4*)&hbar[(size_t)(b0 + bi) * (M_ * D_) + kc + k4];
        }
#pragma unroll
        for (int it = 0; it < 4; ++it) {
            int s = it * 256 + t, kk = s >> 4, e4 = (s & 15) * 4;
            *(float4*)&Bs[kk * PAD + e4] =
                *(const float4*)&W_V[(size_t)(kc + kk) * D_ + e0 + e4];
        }
        __syncthreads();
#pragma unroll 4
        for (int kk = 0; kk < 64; ++kk) {
            float a0 = As[ty * PAD + kk];
            float4 b4 = *(const float4*)&Bs[kk * PAD + tx * 4];
            c0 = fmaf(a0, b4.x, c0);
            c1 = fmaf(a0, b4.y, c1);
            c2 = fmaf(a0, b4.z, c2);
            c3 = fmaf(a0, b4.w, c3);
        }
        __syncthreads();
    }
    int row = b0 + ty, col = e0 + tx * 4;
    float4 s = make_float4(c0, c1, c2, c3);
#pragma unroll
    for (int mm = 0; mm < 4; ++mm) {
        float4 lp = *(const float4*)&lblp[((size_t)mm * B_ + row) * D_ + col];
        s.x += lp.x; s.y += lp.y; s.z += lp.z; s.w += lp.w;
    }
    *(float4*)&out[(size_t)row * D_ + col] = s;
}

// ---------------------------------------------------------------------------
extern "C" void kernel_launch(void* const* d_in, const int* in_sizes, int n_in,
                              void* d_out, int out_size, void* d_ws, size_t ws_size,
                              hipStream_t stream) {
    const float* h_nei     = (const float*)d_in[0];
    const float* ew_anc    = (const float*)d_in[1];
    const float* vmask     = (const float*)d_in[2];
    const float* z_anc     = (const float*)d_in[3];
    const float* lbl_delta = (const float*)d_in[4];
    const float* lbl_w     = (const float*)d_in[5];
    const float* W_Q       = (const float*)d_in[6];
    const float* W_K       = (const float*)d_in[7];
    const float* W_V       = (const float*)d_in[8];
    const float* log_vw    = (const float*)d_in[9];
    float* out = (float*)d_out;

    // ws layout (floats):
    //   Wqk[4*128*256] | Qk[4*2048*256] | hbar[2048*1024] | lblp[4*2048*256]
    float* ws   = (float*)d_ws;
    float* Wqk  = ws;
    float* Qk   = Wqk + (M_ * DZ_ * D_);
    float* hbar = Qk + (M_ * B_ * D_);
    float* lblp = hbar + (B_ * M_ * D_);

    k0_wqk<<<M_ * DZ_, 256, 0, stream>>>(W_Q, W_K, Wqk);

    dim3 g1(B_ / 64, D_ / 64, M_);
    k1_qk<<<g1, 256, 0, stream>>>(z_anc, Wqk, Qk);

    k2_main<<<B_ * M_, 256, 0, stream>>>(h_nei, ew_anc, vmask, lbl_delta,
                                         lbl_w, Qk, log_vw, hbar, lblp);

    dim3 g3(B_ / 16, D_ / 64);
    k3_gemm<<<g3, 256, 0, stream>>>(hbar, W_V, lblp, out);
}